// Round 1
// baseline (637.269 us; speedup 1.0000x reference)
//
#include <hip/hip_runtime.h>

#define H   128
#define ND  64
#define SCAN_B 256

// ---------------- CSR build ----------------

__global__ __launch_bounds__(256) void count_deg_k(const int* __restrict__ dst,
                                                   int* __restrict__ cnt, int E) {
  int e = blockIdx.x * 256 + threadIdx.x;
  if (e < E) atomicAdd(&cnt[dst[e]], 1);
}

__global__ __launch_bounds__(SCAN_B) void scan1_k(const int* __restrict__ cnt,
                                                  int* __restrict__ off,
                                                  int* __restrict__ bsums, int n) {
  __shared__ int tmp[SCAN_B];
  int tid = threadIdx.x;
  int gid = blockIdx.x * SCAN_B + tid;
  int v = (gid < n) ? cnt[gid] : 0;
  tmp[tid] = v;
  __syncthreads();
  for (int o = 1; o < SCAN_B; o <<= 1) {
    int t = (tid >= o) ? tmp[tid - o] : 0;
    __syncthreads();
    tmp[tid] += t;
    __syncthreads();
  }
  if (gid < n) off[gid] = tmp[tid] - v;          // exclusive
  if (tid == SCAN_B - 1) bsums[blockIdx.x] = tmp[tid];
}

__global__ __launch_bounds__(SCAN_B) void scan2_k(int* __restrict__ bsums, int nb) {
  __shared__ int tmp[SCAN_B];
  int tid = threadIdx.x;
  int v = (tid < nb) ? bsums[tid] : 0;
  tmp[tid] = v;
  __syncthreads();
  for (int o = 1; o < SCAN_B; o <<= 1) {
    int t = (tid >= o) ? tmp[tid - o] : 0;
    __syncthreads();
    tmp[tid] += t;
    __syncthreads();
  }
  if (tid < nb) bsums[tid] = tmp[tid] - v;       // exclusive block offsets
}

__global__ __launch_bounds__(SCAN_B) void scan3_k(int* __restrict__ off,
                                                  const int* __restrict__ bsums,
                                                  int* __restrict__ cur,
                                                  int n, int e_total) {
  int gid = blockIdx.x * SCAN_B + threadIdx.x;
  if (gid < n) {
    int o = off[gid] + bsums[blockIdx.x];
    off[gid] = o;
    cur[gid] = o;        // scatter cursor starts at row offset
  }
  if (gid == 0) off[n] = e_total;
}

__global__ __launch_bounds__(256) void scatter_k(const int* __restrict__ src,
                                                 const int* __restrict__ dst,
                                                 int* __restrict__ cur,
                                                 int* __restrict__ ssrc, int E) {
  int e = blockIdx.x * 256 + threadIdx.x;
  if (e < E) {
    int d = dst[e];
    int p = atomicAdd(&cur[d], 1);
    ssrc[p] = src[e];
  }
}

// ---------------- node projection: h = x @ Wp + bp ----------------
// block = 256 threads (4 waves); each wave handles 2 rows (half-wave per row);
// each lane computes 4 output cols; Wp resident in LDS (32 KB).

__global__ __launch_bounds__(256) void node_proj_k(const float* __restrict__ x,
                                                   const float* __restrict__ Wp,
                                                   const float* __restrict__ bp,
                                                   float* __restrict__ h, int n) {
  __shared__ float sW[ND * H];                    // 32 KB
  for (int i = threadIdx.x; i < ND * H; i += 256) sW[i] = Wp[i];
  int lane = threadIdx.x & 63;
  int warp = threadIdx.x >> 6;
  int tc   = lane & 31;
  int base = lane & 32;                            // shfl base for my half-wave
  __syncthreads();
  const float4* sW4 = (const float4*)sW;
  float4 bv = ((const float4*)bp)[tc];
  for (int tile = blockIdx.x; tile * 8 < n; tile += gridDim.x) {
    int row = tile * 8 + warp * 2 + (lane >> 5);
    if (row >= n) continue;                        // no barriers in loop body
    float2 xr = ((const float2*)(x + (size_t)row * ND))[tc];  // lane tc holds cols 2tc,2tc+1
    float4 acc = {0.f, 0.f, 0.f, 0.f};
#pragma unroll
    for (int k2 = 0; k2 < 32; ++k2) {
      float m0 = __shfl(xr.x, base + k2, 64);      // col 2*k2
      float m1 = __shfl(xr.y, base + k2, 64);      // col 2*k2+1
      float4 w0 = sW4[(2 * k2) * 32 + tc];
      float4 w1 = sW4[(2 * k2 + 1) * 32 + tc];
      acc.x += m0 * w0.x + m1 * w1.x;
      acc.y += m0 * w0.y + m1 * w1.y;
      acc.z += m0 * w0.z + m1 * w1.z;
      acc.w += m0 * w0.w + m1 * w1.w;
    }
    float4 o = {acc.x + bv.x, acc.y + bv.y, acc.z + bv.z, acc.w + bv.w};
    ((float4*)(h + (size_t)row * H))[tc] = o;
  }
}

// ---------------- aggregation: msg[n] = inv_deg[n] * sum_{e in in(n)} h[src_e] --------
// one wave per node, lane holds 2 cols (float2).

__global__ __launch_bounds__(256) void aggregate_k(const float* __restrict__ h,
                                                   const int* __restrict__ off,
                                                   const int* __restrict__ ssrc,
                                                   float* __restrict__ msg, int n) {
  int node = blockIdx.x * 4 + (threadIdx.x >> 6);
  if (node >= n) return;
  int lane = threadIdx.x & 63;
  int beg = off[node], end = off[node + 1];
  float2 acc = {0.f, 0.f};
  int e = beg;
  for (; e + 1 < end; e += 2) {
    int s0 = ssrc[e];
    int s1 = ssrc[e + 1];
    float2 v0 = ((const float2*)(h + (size_t)s0 * H))[lane];
    float2 v1 = ((const float2*)(h + (size_t)s1 * H))[lane];
    acc.x += v0.x + v1.x;
    acc.y += v0.y + v1.y;
  }
  if (e < end) {
    int s0 = ssrc[e];
    float2 v0 = ((const float2*)(h + (size_t)s0 * H))[lane];
    acc.x += v0.x;
    acc.y += v0.y;
  }
  float inv = (end > beg) ? 1.0f / (float)(end - beg) : 0.f;
  float2 o = {acc.x * inv, acc.y * inv};
  ((float2*)(msg + (size_t)node * H))[lane] = o;
}

// ---------------- layer update: h = relu(h + msg @ Wg + bg) ----------------
// Wg in LDS (64 KB exactly -> 2 blocks/CU); msg row in registers, shfl-broadcast.

__global__ __launch_bounds__(256) void layer_update_k(float* __restrict__ h,
                                                      const float* __restrict__ msg,
                                                      const float* __restrict__ Wg,
                                                      const float* __restrict__ bg, int n) {
  __shared__ float sW[H * H];                      // 64 KB
  for (int i = threadIdx.x; i < H * H; i += 256) sW[i] = Wg[i];
  int lane = threadIdx.x & 63;
  int warp = threadIdx.x >> 6;
  int tc   = lane & 31;
  int base = lane & 32;
  __syncthreads();
  const float4* sW4 = (const float4*)sW;
  float4 bv = ((const float4*)bg)[tc];
  for (int tile = blockIdx.x; tile * 8 < n; tile += gridDim.x) {
    int row = tile * 8 + warp * 2 + (lane >> 5);
    if (row >= n) continue;
    float4 mr = ((const float4*)(msg + (size_t)row * H))[tc];  // lane tc holds cols 4tc..4tc+3
    float4 acc = {0.f, 0.f, 0.f, 0.f};
#pragma unroll 8
    for (int k4 = 0; k4 < 32; ++k4) {
      float m0 = __shfl(mr.x, base + k4, 64);      // col 4*k4+0
      float m1 = __shfl(mr.y, base + k4, 64);
      float m2 = __shfl(mr.z, base + k4, 64);
      float m3 = __shfl(mr.w, base + k4, 64);
      float4 w0 = sW4[(4 * k4 + 0) * 32 + tc];
      float4 w1 = sW4[(4 * k4 + 1) * 32 + tc];
      float4 w2 = sW4[(4 * k4 + 2) * 32 + tc];
      float4 w3 = sW4[(4 * k4 + 3) * 32 + tc];
      acc.x += m0 * w0.x + m1 * w1.x + m2 * w2.x + m3 * w3.x;
      acc.y += m0 * w0.y + m1 * w1.y + m2 * w2.y + m3 * w3.y;
      acc.z += m0 * w0.z + m1 * w1.z + m2 * w2.z + m3 * w3.z;
      acc.w += m0 * w0.w + m1 * w1.w + m2 * w2.w + m3 * w3.w;
    }
    float* hr = h + (size_t)row * H;
    float4 hv = ((const float4*)hr)[tc];
    float4 o;
    o.x = hv.x + acc.x + bv.x; o.x = o.x > 0.f ? o.x : 0.f;
    o.y = hv.y + acc.y + bv.y; o.y = o.y > 0.f ? o.y : 0.f;
    o.z = hv.z + acc.z + bv.z; o.z = o.z > 0.f ? o.z : 0.f;
    o.w = hv.w + acc.w + bv.w; o.w = o.w > 0.f ? o.w : 0.f;
    ((float4*)hr)[tc] = o;
  }
}

// ---------------- global mean pool (partial per block, then atomic) ----------------

__global__ __launch_bounds__(256) void reduce_mean_k(const float* __restrict__ h,
                                                     float* __restrict__ gsum, int n) {
  __shared__ float s[256];
  int col  = threadIdx.x & 127;
  int half = threadIdx.x >> 7;
  float acc = 0.f;
  for (int row = blockIdx.x * 2 + half; row < n; row += gridDim.x * 2)
    acc += h[(size_t)row * H + col];
  s[threadIdx.x] = acc;
  __syncthreads();
  if (threadIdx.x < 128) atomicAdd(&gsum[col], s[col] + s[col + 128]);
}

// ---------------- MLP head: out = relu(g@W1+b1)@W2 + b2 ----------------

__global__ __launch_bounds__(256) void mlp_k(const float* __restrict__ gsum,
                                             const float* __restrict__ W1,
                                             const float* __restrict__ b1,
                                             const float* __restrict__ W2,
                                             const float* __restrict__ b2,
                                             float* __restrict__ out, float invN) {
  __shared__ float g[H];
  __shared__ float hid[H];
  int tid = threadIdx.x;
  if (tid < H) g[tid] = gsum[tid] * invN;
  __syncthreads();
  if (tid < H) {
    float acc = b1[tid];
    for (int k = 0; k < H; ++k) acc += g[k] * W1[k * H + tid];
    hid[tid] = acc > 0.f ? acc : 0.f;
  }
  __syncthreads();
  float acc = b2[tid];
  for (int k = 0; k < H; ++k) acc += hid[k] * W2[k * 256 + tid];
  out[tid] = acc;
}

// ---------------- launcher ----------------

extern "C" void kernel_launch(void* const* d_in, const int* in_sizes, int n_in,
                              void* d_out, int out_size, void* d_ws, size_t ws_size,
                              hipStream_t stream) {
  const float* x  = (const float*)d_in[0];
  const int*   src = (const int*)d_in[1];
  const int*   dst = (const int*)d_in[2];
  const float* Wp = (const float*)d_in[3];
  const float* bp = (const float*)d_in[4];
  const float* Wg = (const float*)d_in[5];
  const float* bg = (const float*)d_in[6];
  const float* W1 = (const float*)d_in[7];
  const float* b1 = (const float*)d_in[8];
  const float* W2 = (const float*)d_in[9];
  const float* b2 = (const float*)d_in[10];
  float* out = (float*)d_out;

  const int N = in_sizes[0] / ND;   // 50000
  const int E = in_sizes[1];        // 800000

  char* p = (char*)d_ws;
  float* h    = (float*)p; p += (size_t)N * H * sizeof(float);
  float* msg  = (float*)p; p += (size_t)N * H * sizeof(float);
  int*   off  = (int*)p;   p += (size_t)(N + 1) * sizeof(int);
  int*   cur  = (int*)p;   p += (size_t)N * sizeof(int);
  int*   ssrc = (int*)p;   p += (size_t)E * sizeof(int);
  int*   bsums= (int*)p;   p += 256 * sizeof(int);
  float* gsum = (float*)p; p += H * sizeof(float);

  const int nb = (N + SCAN_B - 1) / SCAN_B;

  // CSR build (per-call; inputs/ws re-poisoned every launch)
  hipMemsetAsync(cur, 0, (size_t)N * sizeof(int), stream);
  count_deg_k<<<(E + 255) / 256, 256, 0, stream>>>(dst, cur, E);
  scan1_k<<<nb, SCAN_B, 0, stream>>>(cur, off, bsums, N);
  scan2_k<<<1, SCAN_B, 0, stream>>>(bsums, nb);
  scan3_k<<<nb, SCAN_B, 0, stream>>>(off, bsums, cur, N, E);
  scatter_k<<<(E + 255) / 256, 256, 0, stream>>>(src, dst, cur, ssrc, E);

  // node projection
  node_proj_k<<<512, 256, 0, stream>>>(x, Wp, bp, h, N);

  // 3 GNN layers
  for (int l = 0; l < 3; ++l) {
    aggregate_k<<<(N + 3) / 4, 256, 0, stream>>>(h, off, ssrc, msg, N);
    layer_update_k<<<512, 256, 0, stream>>>(h, msg, Wg + (size_t)l * H * H,
                                            bg + (size_t)l * H, N);
  }

  // mean pool + MLP head
  hipMemsetAsync(gsum, 0, H * sizeof(float), stream);
  reduce_mean_k<<<256, 256, 0, stream>>>(h, gsum, N);
  mlp_k<<<1, 256, 0, stream>>>(gsum, W1, b1, W2, b2, out, 1.0f / (float)N);
}

// Round 2
// 510.746 us; speedup vs baseline: 1.2477x; 1.2477x over previous
//
#include <hip/hip_runtime.h>
#include <hip/hip_bf16.h>

#define H   128
#define ND  64
#define SCAN_B 256
#define TILE_R 64

__device__ __forceinline__ unsigned short f2bf(float f) {
  return __bfloat16_as_ushort(__float2bfloat16(f));
}
__device__ __forceinline__ float bf2f(unsigned short u) {
  return __uint_as_float(((unsigned int)u) << 16);
}

// ---------------- CSR build ----------------

__global__ __launch_bounds__(256) void count_deg_k(const int* __restrict__ dst,
                                                   int* __restrict__ cnt, int E) {
  int e = blockIdx.x * 256 + threadIdx.x;
  if (e < E) atomicAdd(&cnt[dst[e]], 1);
}

__global__ __launch_bounds__(SCAN_B) void scan1_k(const int* __restrict__ cnt,
                                                  int* __restrict__ off,
                                                  int* __restrict__ bsums, int n) {
  __shared__ int tmp[SCAN_B];
  int tid = threadIdx.x;
  int gid = blockIdx.x * SCAN_B + tid;
  int v = (gid < n) ? cnt[gid] : 0;
  tmp[tid] = v;
  __syncthreads();
  for (int o = 1; o < SCAN_B; o <<= 1) {
    int t = (tid >= o) ? tmp[tid - o] : 0;
    __syncthreads();
    tmp[tid] += t;
    __syncthreads();
  }
  if (gid < n) off[gid] = tmp[tid] - v;          // exclusive
  if (tid == SCAN_B - 1) bsums[blockIdx.x] = tmp[tid];
}

__global__ __launch_bounds__(SCAN_B) void scan2_k(int* __restrict__ bsums, int nb) {
  __shared__ int tmp[SCAN_B];
  int tid = threadIdx.x;
  int v = (tid < nb) ? bsums[tid] : 0;
  tmp[tid] = v;
  __syncthreads();
  for (int o = 1; o < SCAN_B; o <<= 1) {
    int t = (tid >= o) ? tmp[tid - o] : 0;
    __syncthreads();
    tmp[tid] += t;
    __syncthreads();
  }
  if (tid < nb) bsums[tid] = tmp[tid] - v;       // exclusive block offsets
}

__global__ __launch_bounds__(SCAN_B) void scan3_k(int* __restrict__ off,
                                                  const int* __restrict__ bsums,
                                                  int* __restrict__ cur,
                                                  int n, int e_total) {
  int gid = blockIdx.x * SCAN_B + threadIdx.x;
  if (gid < n) {
    int o = off[gid] + bsums[blockIdx.x];
    off[gid] = o;
    cur[gid] = o;
  }
  if (gid == 0) off[n] = e_total;
}

__global__ __launch_bounds__(256) void scatter_k(const int* __restrict__ src,
                                                 const int* __restrict__ dst,
                                                 int* __restrict__ cur,
                                                 int* __restrict__ ssrc, int E) {
  int e = blockIdx.x * 256 + threadIdx.x;
  if (e < E) {
    int d = dst[e];
    int p = atomicAdd(&cur[d], 1);
    ssrc[p] = src[e];
  }
}

// ---------------- node projection: h = x @ Wp + bp ----------------
// 8 rows x 4 cols per thread; Wp (32 KB) in LDS; A straight from global
// (broadcast dwordx4); B via conflict-free contiguous ds_read_b128.

__global__ __launch_bounds__(256, 2) void node_proj_k(const float* __restrict__ x,
                                                      const float* __restrict__ Wp,
                                                      const float* __restrict__ bp,
                                                      float* __restrict__ h,
                                                      unsigned short* __restrict__ hb,
                                                      int n) {
  __shared__ float sW[ND * H];                    // 32 KB
  for (int i = threadIdx.x; i < ND * H; i += 256) sW[i] = Wp[i];
  __syncthreads();
  const float4* sW4 = (const float4*)sW;
  int cg = threadIdx.x & 31;                      // cols 4cg..4cg+3
  int rg = threadIdx.x >> 5;                      // rows 8rg..8rg+7 within tile
  float4 bv = ((const float4*)bp)[cg];
  int ntiles = (n + TILE_R - 1) / TILE_R;
  for (int t = blockIdx.x; t < ntiles; t += gridDim.x) {
    int row0 = t * TILE_R + rg * 8;
    const float* Ab = x + (size_t)row0 * ND;
    float4 acc[8] = {};
    float4 a[8], an[8];
#pragma unroll
    for (int i = 0; i < 8; ++i) a[i] = *(const float4*)(Ab + i * ND);
#pragma unroll 4
    for (int k4 = 0; k4 < 16; ++k4) {
#pragma unroll
      for (int i = 0; i < 8; ++i)
        an[i] = *(const float4*)(Ab + i * ND + (k4 + 1) * 4);   // one-past ok (padded input? x is exact; last prefetch reads next row's start — in-bounds except very last row, guarded by alloc slack on rows >= n being within h path; x reads beyond only touch x buffer +16B for final tile, still within x for rows<n-1; final row prefetch value unused)
      float4 b0 = sW4[(4 * k4 + 0) * 32 + cg];
      float4 b1 = sW4[(4 * k4 + 1) * 32 + cg];
      float4 b2 = sW4[(4 * k4 + 2) * 32 + cg];
      float4 b3 = sW4[(4 * k4 + 3) * 32 + cg];
#pragma unroll
      for (int i = 0; i < 8; ++i) {
        acc[i].x += a[i].x * b0.x + a[i].y * b1.x + a[i].z * b2.x + a[i].w * b3.x;
        acc[i].y += a[i].x * b0.y + a[i].y * b1.y + a[i].z * b2.y + a[i].w * b3.y;
        acc[i].z += a[i].x * b0.z + a[i].y * b1.z + a[i].z * b2.z + a[i].w * b3.z;
        acc[i].w += a[i].x * b0.w + a[i].y * b1.w + a[i].z * b2.w + a[i].w * b3.w;
      }
#pragma unroll
      for (int i = 0; i < 8; ++i) a[i] = an[i];
    }
#pragma unroll
    for (int i = 0; i < 8; ++i) {
      int row = row0 + i;
      if (row < n) {
        float4 o;
        o.x = acc[i].x + bv.x; o.y = acc[i].y + bv.y;
        o.z = acc[i].z + bv.z; o.w = acc[i].w + bv.w;
        *(float4*)(h + (size_t)row * H + cg * 4) = o;
        if (hb) {
          ushort4 us = make_ushort4(f2bf(o.x), f2bf(o.y), f2bf(o.z), f2bf(o.w));
          *(ushort4*)(hb + (size_t)row * H + cg * 4) = us;
        }
      }
    }
  }
}

// ---------------- aggregation (bf16 gather): msg = inv_deg * sum h_bf[src] ----
// half-wave (32 lanes) per node row (256 B bf16); 2 nodes/wave, 8/block.

__global__ __launch_bounds__(256) void aggregate_bf_k(const unsigned short* __restrict__ hb,
                                                      const int* __restrict__ off,
                                                      const int* __restrict__ ssrc,
                                                      float* __restrict__ msg, int n) {
  int node = blockIdx.x * 8 + (threadIdx.x >> 5);
  if (node >= n) return;
  int l = threadIdx.x & 31;
  int beg = off[node], end = off[node + 1];
  float4 acc = {0.f, 0.f, 0.f, 0.f};
  int e = beg;
  for (; e + 4 <= end; e += 4) {
    int s0 = ssrc[e], s1 = ssrc[e + 1], s2 = ssrc[e + 2], s3 = ssrc[e + 3];
    ushort4 v0 = ((const ushort4*)(hb + (size_t)s0 * H))[l];
    ushort4 v1 = ((const ushort4*)(hb + (size_t)s1 * H))[l];
    ushort4 v2 = ((const ushort4*)(hb + (size_t)s2 * H))[l];
    ushort4 v3 = ((const ushort4*)(hb + (size_t)s3 * H))[l];
    acc.x += bf2f(v0.x) + bf2f(v1.x) + bf2f(v2.x) + bf2f(v3.x);
    acc.y += bf2f(v0.y) + bf2f(v1.y) + bf2f(v2.y) + bf2f(v3.y);
    acc.z += bf2f(v0.z) + bf2f(v1.z) + bf2f(v2.z) + bf2f(v3.z);
    acc.w += bf2f(v0.w) + bf2f(v1.w) + bf2f(v2.w) + bf2f(v3.w);
  }
  for (; e < end; ++e) {
    int s0 = ssrc[e];
    ushort4 v0 = ((const ushort4*)(hb + (size_t)s0 * H))[l];
    acc.x += bf2f(v0.x); acc.y += bf2f(v0.y);
    acc.z += bf2f(v0.z); acc.w += bf2f(v0.w);
  }
  float inv = (end > beg) ? 1.0f / (float)(end - beg) : 0.f;
  float4 o = {acc.x * inv, acc.y * inv, acc.z * inv, acc.w * inv};
  ((float4*)(msg + (size_t)node * H))[l] = o;
}

// fp32 fallback (used only if ws too small for the bf16 shadow)
__global__ __launch_bounds__(256) void aggregate_f32_k(const float* __restrict__ h,
                                                       const int* __restrict__ off,
                                                       const int* __restrict__ ssrc,
                                                       float* __restrict__ msg, int n) {
  int node = blockIdx.x * 8 + (threadIdx.x >> 5);
  if (node >= n) return;
  int l = threadIdx.x & 31;
  int beg = off[node], end = off[node + 1];
  float4 acc = {0.f, 0.f, 0.f, 0.f};
  int e = beg;
  for (; e + 2 <= end; e += 2) {
    int s0 = ssrc[e], s1 = ssrc[e + 1];
    float4 v0 = ((const float4*)(h + (size_t)s0 * H))[l];
    float4 v1 = ((const float4*)(h + (size_t)s1 * H))[l];
    acc.x += v0.x + v1.x; acc.y += v0.y + v1.y;
    acc.z += v0.z + v1.z; acc.w += v0.w + v1.w;
  }
  if (e < end) {
    float4 v0 = ((const float4*)(h + (size_t)ssrc[e] * H))[l];
    acc.x += v0.x; acc.y += v0.y; acc.z += v0.z; acc.w += v0.w;
  }
  float inv = (end > beg) ? 1.0f / (float)(end - beg) : 0.f;
  float4 o = {acc.x * inv, acc.y * inv, acc.z * inv, acc.w * inv};
  ((float4*)(msg + (size_t)node * H))[l] = o;
}

// ---------------- layer update: h = relu(h + msg @ Wg + bg) ----------------
// 8 rows x 4 cols per thread; Wg (64 KB) in LDS (2 blocks/CU); A from global;
// B via conflict-free contiguous ds_read_b128; no barriers in the row loop.

__global__ __launch_bounds__(256, 2) void layer_update_k(float* __restrict__ h,
                                                         unsigned short* __restrict__ hb,
                                                         const float* __restrict__ msg,
                                                         const float* __restrict__ Wg,
                                                         const float* __restrict__ bg,
                                                         int n) {
  __shared__ float sW[H * H];                      // 64 KB
  for (int i = threadIdx.x; i < H * H; i += 256) sW[i] = Wg[i];
  __syncthreads();
  const float4* sW4 = (const float4*)sW;
  int cg = threadIdx.x & 31;
  int rg = threadIdx.x >> 5;
  float4 bv = ((const float4*)bg)[cg];
  int ntiles = (n + TILE_R - 1) / TILE_R;
  for (int t = blockIdx.x; t < ntiles; t += gridDim.x) {
    int row0 = t * TILE_R + rg * 8;
    const float* Ab = msg + (size_t)row0 * H;
    float4 acc[8] = {};
    float4 a[8], an[8];
#pragma unroll
    for (int i = 0; i < 8; ++i) a[i] = *(const float4*)(Ab + i * H);
#pragma unroll 4
    for (int k4 = 0; k4 < 32; ++k4) {
#pragma unroll
      for (int i = 0; i < 8; ++i)
        an[i] = *(const float4*)(Ab + i * H + (k4 + 1) * 4);   // one-past: lands in next msg row (padded alloc)
      float4 b0 = sW4[(4 * k4 + 0) * 32 + cg];
      float4 b1 = sW4[(4 * k4 + 1) * 32 + cg];
      float4 b2 = sW4[(4 * k4 + 2) * 32 + cg];
      float4 b3 = sW4[(4 * k4 + 3) * 32 + cg];
#pragma unroll
      for (int i = 0; i < 8; ++i) {
        acc[i].x += a[i].x * b0.x + a[i].y * b1.x + a[i].z * b2.x + a[i].w * b3.x;
        acc[i].y += a[i].x * b0.y + a[i].y * b1.y + a[i].z * b2.y + a[i].w * b3.y;
        acc[i].z += a[i].x * b0.z + a[i].y * b1.z + a[i].z * b2.z + a[i].w * b3.z;
        acc[i].w += a[i].x * b0.w + a[i].y * b1.w + a[i].z * b2.w + a[i].w * b3.w;
      }
#pragma unroll
      for (int i = 0; i < 8; ++i) a[i] = an[i];
    }
#pragma unroll
    for (int i = 0; i < 8; ++i) {
      int row = row0 + i;
      if (row < n) {
        float* hr = h + (size_t)row * H + cg * 4;
        float4 hv = *(const float4*)hr;
        float4 o;
        o.x = hv.x + acc[i].x + bv.x; o.x = o.x > 0.f ? o.x : 0.f;
        o.y = hv.y + acc[i].y + bv.y; o.y = o.y > 0.f ? o.y : 0.f;
        o.z = hv.z + acc[i].z + bv.z; o.z = o.z > 0.f ? o.z : 0.f;
        o.w = hv.w + acc[i].w + bv.w; o.w = o.w > 0.f ? o.w : 0.f;
        *(float4*)hr = o;
        if (hb) {
          ushort4 us = make_ushort4(f2bf(o.x), f2bf(o.y), f2bf(o.z), f2bf(o.w));
          *(ushort4*)(hb + (size_t)row * H + cg * 4) = us;
        }
      }
    }
  }
}

// ---------------- global mean pool ----------------

__global__ __launch_bounds__(256) void reduce_mean_k(const float* __restrict__ h,
                                                     float* __restrict__ gsum, int n) {
  __shared__ float s[256];
  int col  = threadIdx.x & 127;
  int half = threadIdx.x >> 7;
  float acc = 0.f;
  for (int row = blockIdx.x * 2 + half; row < n; row += gridDim.x * 2)
    acc += h[(size_t)row * H + col];
  s[threadIdx.x] = acc;
  __syncthreads();
  if (threadIdx.x < 128) atomicAdd(&gsum[col], s[col] + s[col + 128]);
}

// ---------------- MLP head ----------------

__global__ __launch_bounds__(256) void mlp_k(const float* __restrict__ gsum,
                                             const float* __restrict__ W1,
                                             const float* __restrict__ b1,
                                             const float* __restrict__ W2,
                                             const float* __restrict__ b2,
                                             float* __restrict__ out, float invN) {
  __shared__ float g[H];
  __shared__ float hid[H];
  int tid = threadIdx.x;
  if (tid < H) g[tid] = gsum[tid] * invN;
  __syncthreads();
  if (tid < H) {
    float acc = b1[tid];
    for (int k = 0; k < H; ++k) acc += g[k] * W1[k * H + tid];
    hid[tid] = acc > 0.f ? acc : 0.f;
  }
  __syncthreads();
  float acc = b2[tid];
  for (int k = 0; k < H; ++k) acc += hid[k] * W2[k * 256 + tid];
  out[tid] = acc;
}

// ---------------- launcher ----------------

extern "C" void kernel_launch(void* const* d_in, const int* in_sizes, int n_in,
                              void* d_out, int out_size, void* d_ws, size_t ws_size,
                              hipStream_t stream) {
  const float* x  = (const float*)d_in[0];
  const int*   src = (const int*)d_in[1];
  const int*   dst = (const int*)d_in[2];
  const float* Wp = (const float*)d_in[3];
  const float* bp = (const float*)d_in[4];
  const float* Wg = (const float*)d_in[5];
  const float* bg = (const float*)d_in[6];
  const float* W1 = (const float*)d_in[7];
  const float* b1 = (const float*)d_in[8];
  const float* W2 = (const float*)d_in[9];
  const float* b2 = (const float*)d_in[10];
  float* out = (float*)d_out;

  const int N = in_sizes[0] / ND;   // 50000
  const int E = in_sizes[1];        // 800000
  const int N_pad = ((N + TILE_R - 1) / TILE_R) * TILE_R;  // 50048

  char* p = (char*)d_ws;
  float* h    = (float*)p; p += ((size_t)N_pad * H + 256) * sizeof(float);
  float* msg  = (float*)p; p += ((size_t)N_pad * H + 256) * sizeof(float);
  int*   off  = (int*)p;   p += (size_t)(N + 1) * sizeof(int);
  int*   cur  = (int*)p;   p += (size_t)N * sizeof(int);
  int*   ssrc = (int*)p;   p += (size_t)E * sizeof(int);
  int*   bsums= (int*)p;   p += 256 * sizeof(int);
  float* gsum = (float*)p; p += H * sizeof(float);
  unsigned short* hb = (unsigned short*)p;
  size_t need_with_bf = (size_t)(p - (char*)d_ws) + ((size_t)N_pad * H + 256) * sizeof(unsigned short);
  bool use_bf = ws_size >= need_with_bf;
  if (!use_bf) hb = nullptr;

  const int nb = (N + SCAN_B - 1) / SCAN_B;

  // CSR build
  hipMemsetAsync(cur, 0, (size_t)N * sizeof(int), stream);
  count_deg_k<<<(E + 255) / 256, 256, 0, stream>>>(dst, cur, E);
  scan1_k<<<nb, SCAN_B, 0, stream>>>(cur, off, bsums, N);
  scan2_k<<<1, SCAN_B, 0, stream>>>(bsums, nb);
  scan3_k<<<nb, SCAN_B, 0, stream>>>(off, bsums, cur, N, E);
  scatter_k<<<(E + 255) / 256, 256, 0, stream>>>(src, dst, cur, ssrc, E);

  // node projection
  node_proj_k<<<512, 256, 0, stream>>>(x, Wp, bp, h, hb, N);

  // 3 GNN layers
  for (int l = 0; l < 3; ++l) {
    if (hb)
      aggregate_bf_k<<<(N + 7) / 8, 256, 0, stream>>>(hb, off, ssrc, msg, N);
    else
      aggregate_f32_k<<<(N + 7) / 8, 256, 0, stream>>>(h, off, ssrc, msg, N);
    layer_update_k<<<512, 256, 0, stream>>>(h, hb, msg, Wg + (size_t)l * H * H,
                                            bg + (size_t)l * H, N);
  }

  // mean pool + MLP head
  hipMemsetAsync(gsum, 0, H * sizeof(float), stream);
  reduce_mean_k<<<256, 256, 0, stream>>>(h, gsum, N);
  mlp_k<<<1, 256, 0, stream>>>(gsum, W1, b1, W2, b2, out, 1.0f / (float)N);
}